// Round 1
// baseline (12802.843 us; speedup 1.0000x reference)
//
#include <hip/hip_runtime.h>
#include <float.h>

#define NQ      4096          // B*T
#define NKEYS   65536
#define DKDIM   128
#define DVDIM   128
#define TOPK_N  32
#define BQ      32            // queries per block
#define NKT     256           // keys per tile
#define KD      16            // dim chunk staged in LDS
#define NSPLIT  8
#define KPS     (NKEYS / NSPLIT)   // 8192 keys per split
#define NTILES  (KPS / NKT)        // 32 tiles per split
#define NOUT    ((size_t)NQ * TOPK_N * DKDIM)   // 16777216 floats per output tensor

// ---------------------------------------------------------------------------
// Kernel 1: fused fp32 score GEMM + per-query top-32 (per key-split partial).
// Each block: 32 queries x 8192 keys. Scores accumulated as a single
// sequential fmaf chain over d=0..127 (matches BLAS sgemm microkernel order).
// ---------------------------------------------------------------------------
__global__ __launch_bounds__(256) void score_topk_kernel(
    const float* __restrict__ qg, const float* __restrict__ keys,
    float* __restrict__ pscore, int* __restrict__ pidx)
{
    __shared__ float qt[DKDIM][BQ + 4];     // [d][q], stride 36 (16B-aligned rows, conflict-padded)
    __shared__ float kt[KD][NKT + 4];       // [d][k], stride 260
    __shared__ float sc[BQ][NKT + 4];       // score tile, stride 260
    __shared__ float ts[BQ][TOPK_N + 1];    // sorted top-32 scores, stride 33
    __shared__ int   ti[BQ][TOPK_N + 1];    // matching indices

    const int tid   = threadIdx.x;
    const int q0    = blockIdx.x * BQ;
    const int nbase = blockIdx.y * KPS;

    // Stage q-tile transposed (once per block).
    {
        const int qi  = tid >> 3;      // 0..31
        const int slo = tid & 7;
#pragma unroll
        for (int r = 0; r < 4; ++r) {
            const int slot = slo + 8 * r;  // float4 slot 0..31
            const float4 v = *(const float4*)(qg + (size_t)(q0 + qi) * DKDIM + 4 * slot);
            qt[4 * slot + 0][qi] = v.x;
            qt[4 * slot + 1][qi] = v.y;
            qt[4 * slot + 2][qi] = v.z;
            qt[4 * slot + 3][qi] = v.w;
        }
    }
    for (int i = tid; i < BQ * TOPK_N; i += 256) {
        const int qq = i >> 5, ss = i & 31;
        ts[qq][ss] = -FLT_MAX;
        ti[qq][ss] = 0;
    }
    __syncthreads();

    const int tq  = tid >> 5;   // 0..7  -> 4 queries each
    const int tk  = tid & 31;   // 0..31 -> 8 keys each
    const int myq = tq * 4;
    const int myk = tk * 8;

    for (int tile = 0; tile < NTILES; ++tile) {
        const int n0 = nbase + tile * NKT;
        float acc[4][8];
#pragma unroll
        for (int i = 0; i < 4; ++i)
#pragma unroll
            for (int j = 0; j < 8; ++j) acc[i][j] = 0.f;

        for (int c = 0; c < DKDIM / KD; ++c) {
            const int d0 = c * KD;
            // Stage 256 keys x 16 dims, transposed.
            {
                const int slot = tid & 3;   // float4 slot within 16-dim chunk
                const int krow = tid >> 2;  // 0..63
#pragma unroll
                for (int r = 0; r < 4; ++r) {
                    const int kl = krow + 64 * r;   // 0..255
                    const float4 v = *(const float4*)(keys + (size_t)(n0 + kl) * DKDIM + d0 + 4 * slot);
                    kt[4 * slot + 0][kl] = v.x;
                    kt[4 * slot + 1][kl] = v.y;
                    kt[4 * slot + 2][kl] = v.z;
                    kt[4 * slot + 3][kl] = v.w;
                }
            }
            __syncthreads();
#pragma unroll
            for (int d = 0; d < KD; ++d) {
                const float4 a  = *(const float4*)&qt[d0 + d][myq];
                const float4 b0 = *(const float4*)&kt[d][myk];
                const float4 b1 = *(const float4*)&kt[d][myk + 4];
                const float av[4] = {a.x, a.y, a.z, a.w};
                const float bv[8] = {b0.x, b0.y, b0.z, b0.w, b1.x, b1.y, b1.z, b1.w};
#pragma unroll
                for (int i = 0; i < 4; ++i)
#pragma unroll
                    for (int j = 0; j < 8; ++j)
                        acc[i][j] = fmaf(av[i], bv[j], acc[i][j]);
            }
            __syncthreads();
        }
        // Dump score tile to LDS.
#pragma unroll
        for (int i = 0; i < 4; ++i) {
            *(float4*)&sc[myq + i][myk]     = make_float4(acc[i][0], acc[i][1], acc[i][2], acc[i][3]);
            *(float4*)&sc[myq + i][myk + 4] = make_float4(acc[i][4], acc[i][5], acc[i][6], acc[i][7]);
        }
        __syncthreads();
        // One thread per query maintains its sorted top-32 (stable: strict compares
        // keep the earlier/lower index on ties, matching lax.top_k).
        if (tid < BQ) {
            const int qq = tid;
            float th = ts[qq][TOPK_N - 1];
            for (int j = 0; j < NKT; ++j) {
                const float s = sc[qq][j];
                if (s > th) {
                    int p = TOPK_N - 1;
                    while (p > 0 && ts[qq][p - 1] < s) {
                        ts[qq][p] = ts[qq][p - 1];
                        ti[qq][p] = ti[qq][p - 1];
                        --p;
                    }
                    ts[qq][p] = s;
                    ti[qq][p] = n0 + j;
                    th = ts[qq][TOPK_N - 1];
                }
            }
        }
        __syncthreads();
    }

    // Write partial sorted lists.
    for (int i = tid; i < BQ * TOPK_N; i += 256) {
        const int qq = i >> 5, ss = i & 31;
        const size_t o = (((size_t)(q0 + qq)) * NSPLIT + blockIdx.y) * TOPK_N + ss;
        pscore[o] = ts[qq][ss];
        pidx[o]   = ti[qq][ss];
    }
}

// ---------------------------------------------------------------------------
// Kernel 2: per-query 8-way merge of sorted partials + gather K/V rows.
// ---------------------------------------------------------------------------
__global__ __launch_bounds__(256) void merge_gather_kernel(
    const float* __restrict__ keys, const float* __restrict__ values,
    const float* __restrict__ pscore, const int* __restrict__ pidx,
    float* __restrict__ out)
{
    __shared__ int fidx[TOPK_N];
    const int bt = blockIdx.x;

    if (threadIdx.x == 0) {
        const float* ps = pscore + (size_t)bt * NSPLIT * TOPK_N;
        const int*   pi = pidx   + (size_t)bt * NSPLIT * TOPK_N;
        int h[NSPLIT];
#pragma unroll
        for (int s = 0; s < NSPLIT; ++s) h[s] = 0;
        for (int o = 0; o < TOPK_N; ++o) {
            float best = -FLT_MAX;
            int bs = 0;
#pragma unroll
            for (int s = 0; s < NSPLIT; ++s) {
                if (h[s] < TOPK_N) {
                    const float v = ps[s * TOPK_N + h[s]];
                    if (v > best) { best = v; bs = s; }   // strict: ties keep lower split = lower index
                }
            }
            fidx[o] = pi[bs * TOPK_N + h[bs]];
            ++h[bs];
        }
    }
    __syncthreads();

    const int lane = threadIdx.x & 31;   // 32 float4 = 128 floats per row
    const int rb   = threadIdx.x >> 5;   // 8 rows per pass
#pragma unroll
    for (int r = 0; r < 4; ++r) {
        const int row = rb + 8 * r;      // 0..31
        const int n   = fidx[row];
        const float4 kv = *(const float4*)(keys   + (size_t)n * DKDIM + 4 * lane);
        const float4 vv = *(const float4*)(values + (size_t)n * DVDIM + 4 * lane);
        const size_t ob = ((size_t)bt * TOPK_N + row) * DKDIM + 4 * lane;
        *(float4*)(out + ob)        = kv;
        *(float4*)(out + NOUT + ob) = vv;
    }
}

extern "C" void kernel_launch(void* const* d_in, const int* in_sizes, int n_in,
                              void* d_out, int out_size, void* d_ws, size_t ws_size,
                              hipStream_t stream)
{
    const float* q      = (const float*)d_in[0];
    const float* keys   = (const float*)d_in[1];
    const float* values = (const float*)d_in[2];
    // d_in[3] = topk scalar (fixed 32), ignored.
    float* out    = (float*)d_out;
    float* pscore = (float*)d_ws;                                              // 4 MB
    int*   pidx   = (int*)((char*)d_ws + (size_t)NQ * NSPLIT * TOPK_N * 4);    // 4 MB

    score_topk_kernel<<<dim3(NQ / BQ, NSPLIT), 256, 0, stream>>>(q, keys, pscore, pidx);
    merge_gather_kernel<<<NQ, 256, 0, stream>>>(keys, values, pscore, pidx, out);
}

// Round 2
// 4313.141 us; speedup vs baseline: 2.9683x; 2.9683x over previous
//
#include <hip/hip_runtime.h>
#include <float.h>

#define NQ      4096          // B*T
#define NKEYS   65536
#define DKDIM   128
#define DVDIM   128
#define TOPK_N  32
#define BQ      32            // queries per block
#define NKT     256           // keys per tile
#define KD      16            // dim chunk staged in LDS
#define NSPLIT  8
#define KPS     (NKEYS / NSPLIT)   // 8192 keys per split
#define NTILES  (KPS / NKT)        // 32 tiles per split
#define NOUT    ((size_t)NQ * TOPK_N * DKDIM)   // floats per output tensor

// ---------------------------------------------------------------------------
// Kernel 1: fused fp32 score GEMM + per-query top-32 pool (per key-split).
// Block: 32 queries x 8192 keys. Wave w owns queries 8w..8w+7 for both the
// register tile (8q x 4k per thread) and the selection phase.
// Scores: single sequential fmaf chain over d=0..127 (bitwise-matches ref).
// Selection: ballot-filtered replace-min pool, wave-uniform control flow.
// ---------------------------------------------------------------------------
__global__ __launch_bounds__(256) void score_topk_kernel(
    const float* __restrict__ qg, const float* __restrict__ keys,
    float* __restrict__ pscore, int* __restrict__ pidx)
{
    __shared__ float qt[DKDIM][BQ + 4];       // [d][q], stride 36
    __shared__ float kt[KD][NKT + 4];         // [d][k], stride 260
    __shared__ float pv[BQ][TOPK_N + 1];      // top-32 pools (unsorted)
    __shared__ int   pix[BQ][TOPK_N + 1];
    __shared__ float pminv[BQ];               // cached pool min
    __shared__ int   pminp[BQ];               // cached pool argmin slot

    const int tid   = threadIdx.x;
    const int q0    = blockIdx.x * BQ;
    const int nbase = blockIdx.y * KPS;

    // Stage q-tile transposed (once per block).
    {
        const int qi  = tid >> 3;
        const int slo = tid & 7;
#pragma unroll
        for (int r = 0; r < 4; ++r) {
            const int slot = slo + 8 * r;
            const float4 v = *(const float4*)(qg + (size_t)(q0 + qi) * DKDIM + 4 * slot);
            qt[4 * slot + 0][qi] = v.x;
            qt[4 * slot + 1][qi] = v.y;
            qt[4 * slot + 2][qi] = v.z;
            qt[4 * slot + 3][qi] = v.w;
        }
    }
    for (int i = tid; i < BQ * TOPK_N; i += 256) {
        pv[i >> 5][i & 31] = -FLT_MAX;
        pix[i >> 5][i & 31] = 0;
    }
    if (tid < BQ) { pminv[tid] = -FLT_MAX; pminp[tid] = 0; }
    __syncthreads();

    const int lane = tid & 63;
    const int tq   = tid >> 6;    // wave id: 0..3 -> 8 queries each
    const int myq  = tq * 8;
    const int myk  = lane * 4;    // 4 consecutive keys per thread

    for (int tile = 0; tile < NTILES; ++tile) {
        const int n0 = nbase + tile * NKT;
        float acc[8][4];
#pragma unroll
        for (int i = 0; i < 8; ++i)
#pragma unroll
            for (int j = 0; j < 4; ++j) acc[i][j] = 0.f;

        for (int c = 0; c < DKDIM / KD; ++c) {
            const int d0 = c * KD;
            // Stage 256 keys x 16 dims, transposed.
            {
                const int slot = tid & 3;
                const int krow = tid >> 2;
#pragma unroll
                for (int r = 0; r < 4; ++r) {
                    const int kl = krow + 64 * r;
                    const float4 v = *(const float4*)(keys + (size_t)(n0 + kl) * DKDIM + d0 + 4 * slot);
                    kt[4 * slot + 0][kl] = v.x;
                    kt[4 * slot + 1][kl] = v.y;
                    kt[4 * slot + 2][kl] = v.z;
                    kt[4 * slot + 3][kl] = v.w;
                }
            }
            __syncthreads();
#pragma unroll
            for (int d = 0; d < KD; ++d) {
                const float4 a0 = *(const float4*)&qt[d0 + d][myq];      // broadcast
                const float4 a1 = *(const float4*)&qt[d0 + d][myq + 4];  // broadcast
                const float4 b  = *(const float4*)&kt[d][myk];           // lane-consecutive
                const float av[8] = {a0.x, a0.y, a0.z, a0.w, a1.x, a1.y, a1.z, a1.w};
                const float bv[4] = {b.x, b.y, b.z, b.w};
#pragma unroll
                for (int i = 0; i < 8; ++i)
#pragma unroll
                    for (int j = 0; j < 4; ++j)
                        acc[i][j] = fmaf(av[i], bv[j], acc[i][j]);
            }
            __syncthreads();
        }

        // Selection: wave-local, scores stay in registers.
        // Lane holds keys n0 + lane*4 + c for its wave's 8 queries.
        for (int qq = 0; qq < 8; ++qq) {
            const int q = myq + qq;
            float vmin = pminv[q];
            int   mpos = pminp[q];
#pragma unroll
            for (int c = 0; c < 4; ++c) {
                const float s = acc[qq][c];
                unsigned long long m = __ballot(s > vmin);
                while (m) {   // m is wave-uniform -> uniform loop
                    const int src = __builtin_ctzll(m);
                    m &= m - 1;
                    const float v = __shfl(s, src);
                    if (v > vmin) {   // uniform (v broadcast, vmin uniform)
                        if (lane == 0) {
                            pv[q][mpos]  = v;
                            pix[q][mpos] = n0 + src * 4 + c;
                        }
                        // Recompute pool argmin: 64-lane butterfly, lanes>=32 sentinel.
                        float v0 = (lane < 32) ? pv[q][lane] : FLT_MAX;
                        int   p0 = lane & 31;
#pragma unroll
                        for (int off = 32; off > 0; off >>= 1) {
                            const float ov = __shfl_xor(v0, off);
                            const int   op = __shfl_xor(p0, off);
                            if (ov < v0) { v0 = ov; p0 = op; }
                        }
                        vmin = v0;
                        mpos = p0;
                    }
                }
            }
            if (lane == 0) { pminv[q] = vmin; pminp[q] = mpos; }
        }
        // No barrier needed: selection touches only this wave's pool rows; the
        // staging barrier at the top of the next chunk synchronizes kt reuse.
    }
    __syncthreads();

    // Write unsorted pools: layout [query][split][slot].
    for (int i = tid; i < BQ * TOPK_N; i += 256) {
        const int qq = i >> 5, ss = i & 31;
        const size_t o = (((size_t)(q0 + qq)) * NSPLIT + blockIdx.y) * TOPK_N + ss;
        pscore[o] = pv[qq][ss];
        pidx[o]   = pix[qq][ss];
    }
}

// ---------------------------------------------------------------------------
// Kernel 2: per-query bitonic sort of 256 candidates (desc, tie -> lower idx),
// then gather top-32 K/V rows. One block per query.
// ---------------------------------------------------------------------------
__global__ __launch_bounds__(256) void merge_gather_kernel(
    const float* __restrict__ keys, const float* __restrict__ values,
    const float* __restrict__ pscore, const int* __restrict__ pidx,
    float* __restrict__ out)
{
    __shared__ float ss[NSPLIT * TOPK_N];
    __shared__ int   si[NSPLIT * TOPK_N];
    const int bt  = blockIdx.x;
    const int tid = threadIdx.x;

    ss[tid] = pscore[(size_t)bt * NSPLIT * TOPK_N + tid];
    si[tid] = pidx[(size_t)bt * NSPLIT * TOPK_N + tid];
    __syncthreads();

    for (int k = 2; k <= NSPLIT * TOPK_N; k <<= 1) {
        for (int j = k >> 1; j > 0; j >>= 1) {
            const int ixj = tid ^ j;
            if (ixj > tid) {
                const bool dirDesc = ((tid & k) == 0);
                const float sa = ss[tid], sb = ss[ixj];
                const int   ia = si[tid], ib = si[ixj];
                const bool before = (sa > sb) || (sa == sb && ia < ib);
                if (before != dirDesc) {
                    ss[tid] = sb; ss[ixj] = sa;
                    si[tid] = ib; si[ixj] = ia;
                }
            }
            __syncthreads();
        }
    }

    // Gather: 32 rows x 128 floats for K and V.
    const int lane = tid & 31;
    const int rb   = tid >> 5;
#pragma unroll
    for (int r = 0; r < 4; ++r) {
        const int row = rb + 8 * r;
        const int n   = si[row];
        const float4 kv = *(const float4*)(keys   + (size_t)n * DKDIM + 4 * lane);
        const float4 vv = *(const float4*)(values + (size_t)n * DVDIM + 4 * lane);
        const size_t ob = ((size_t)bt * TOPK_N + row) * DKDIM + 4 * lane;
        *(float4*)(out + ob)        = kv;
        *(float4*)(out + NOUT + ob) = vv;
    }
}

extern "C" void kernel_launch(void* const* d_in, const int* in_sizes, int n_in,
                              void* d_out, int out_size, void* d_ws, size_t ws_size,
                              hipStream_t stream)
{
    const float* q      = (const float*)d_in[0];
    const float* keys   = (const float*)d_in[1];
    const float* values = (const float*)d_in[2];
    float* out    = (float*)d_out;
    float* pscore = (float*)d_ws;                                              // 4 MB
    int*   pidx   = (int*)((char*)d_ws + (size_t)NQ * NSPLIT * TOPK_N * 4);    // 4 MB

    score_topk_kernel<<<dim3(NQ / BQ, NSPLIT), 256, 0, stream>>>(q, keys, pscore, pidx);
    merge_gather_kernel<<<NQ, 256, 0, stream>>>(keys, values, pscore, pidx, out);
}

// Round 3
// 1235.262 us; speedup vs baseline: 10.3645x; 3.4917x over previous
//
#include <hip/hip_runtime.h>
#include <float.h>

#define NQ      4096
#define NKEYS   65536
#define DKDIM   128
#define DVDIM   128
#define TOPK_N  32
#define NSPLIT  8
#define KPS     (NKEYS / NSPLIT)        // 8192 keys per split
#define BQ      64                      // queries per block (4 waves x 16)
#define NCAND   (NSPLIT * TOPK_N)       // 256 candidates per query
#define NOUT    ((size_t)NQ * TOPK_N * DKDIM)

typedef __attribute__((ext_vector_type(8))) short short8;   // 8 bf16
typedef __attribute__((ext_vector_type(4))) float v4f;      // MFMA acc

__device__ inline unsigned short f2bf(float f) {            // RNE fp32->bf16
    unsigned int u = __float_as_uint(f);
    return (unsigned short)((u + 0x7FFFu + ((u >> 16) & 1u)) >> 16);
}

// ---------------------------------------------------------------------------
// Kernel A: convert q and keys to bf16 (workspace).
// ---------------------------------------------------------------------------
__global__ __launch_bounds__(256) void convert_kernel(
    const float* __restrict__ q, const float* __restrict__ keys,
    unsigned short* __restrict__ qbf, unsigned short* __restrict__ kbf)
{
    const size_t QG = (size_t)NQ * DKDIM / 8;       // 65536 groups of 8
    const size_t KG = (size_t)NKEYS * DKDIM / 8;    // 1048576
    const size_t g  = (size_t)blockIdx.x * 256 + threadIdx.x;
    if (g >= QG + KG) return;
    const float* src;
    unsigned short* dst;
    if (g < QG) { src = q + g * 8;         dst = qbf + g * 8; }
    else        { const size_t h = g - QG; src = keys + h * 8; dst = kbf + h * 8; }
    const float4 a = ((const float4*)src)[0];
    const float4 b = ((const float4*)src)[1];
    short8 o;
    o[0] = (short)f2bf(a.x); o[1] = (short)f2bf(a.y);
    o[2] = (short)f2bf(a.z); o[3] = (short)f2bf(a.w);
    o[4] = (short)f2bf(b.x); o[5] = (short)f2bf(b.y);
    o[6] = (short)f2bf(b.z); o[7] = (short)f2bf(b.w);
    *(short8*)dst = o;
}

// ---------------------------------------------------------------------------
// Kernel B: bf16 MFMA approx scores + per-(query,split) approx-top-32 pools.
// Grid (NQ/BQ, NSPLIT). Block 256 = 4 waves; wave w owns queries
// [blockIdx.x*64 + 16w, +16) and scans all 8192 split keys, 16 per iter.
// MFMA 16x16x32: A = Q-tile (lane: Q[q0+(l&15)][ (l>>4)*8+j + 32t ]),
//                B = K-tile (lane: K[n0+(l&15)][ same d ]),
//                D: lane l, reg r -> S[q0 + (l>>4)*4 + r][n0 + (l&15)].
// Selection: per 16-lane quad (owns queries q0+quad*4+r), ballot-filtered
// replace-min pools in LDS, argmin via intra-quad butterfly.
// ---------------------------------------------------------------------------
__global__ __launch_bounds__(256) void score_select_kernel(
    const unsigned short* __restrict__ qbf, const unsigned short* __restrict__ kbf,
    int* __restrict__ cand)
{
    __shared__ float pv[BQ][TOPK_N];    // 8 KB, wave-private rows
    __shared__ int   pix[BQ][TOPK_N];   // 8 KB

    const int tid  = threadIdx.x;
    const int wave = tid >> 6;
    const int lane = tid & 63;
    const int l16  = lane & 15;
    const int quad = lane >> 4;
    const int q0   = blockIdx.x * BQ + wave * 16;
    const int nbase = blockIdx.y * KPS;

    for (int i = tid; i < BQ * TOPK_N; i += 256) {
        pv[i >> 5][i & 31]  = -FLT_MAX;
        pix[i >> 5][i & 31] = 0;
    }
    __syncthreads();

    // A fragments (q-tile), resident for the whole kernel.
    short8 afrag[4];
#pragma unroll
    for (int t = 0; t < 4; ++t)
        afrag[t] = *(const short8*)(qbf + (size_t)(q0 + l16) * DKDIM + t * 32 + quad * 8);

    // Cached pool min/argmin for this lane's quad queries (q0 + quad*4 + r).
    float vm[4]; int pp[4];
#pragma unroll
    for (int r = 0; r < 4; ++r) { vm[r] = -FLT_MAX; pp[r] = 0; }

    for (int it = 0; it < KPS / 16; ++it) {
        const int n0 = nbase + it * 16;
        const unsigned short* kb = kbf + (size_t)(n0 + l16) * DKDIM + quad * 8;
        v4f acc = {0.f, 0.f, 0.f, 0.f};
#pragma unroll
        for (int t = 0; t < 4; ++t) {
            const short8 bfrag = *(const short8*)(kb + t * 32);
            acc = __builtin_amdgcn_mfma_f32_16x16x32_bf16(afrag[t], bfrag, acc, 0, 0, 0);
        }
#pragma unroll
        for (int r = 0; r < 4; ++r) {
            unsigned long long m = __ballot(acc[r] > vm[r]);
            while (m) {   // m wave-uniform
                // One hit per quad per round; clear mask computed uniformly.
                unsigned long long clearm = 0;
#pragma unroll
                for (int p = 0; p < 4; ++p) {
                    const unsigned int mp = (unsigned int)(m >> (p * 16)) & 0xFFFFu;
                    if (mp) clearm |= 1ULL << (p * 16 + __builtin_ctz(mp));
                }
                const unsigned int mq = (unsigned int)(m >> (quad * 16)) & 0xFFFFu;
                const bool has = (mq != 0);
                const int  src = has ? (quad * 16 + __builtin_ctz(mq)) : lane;
                const float v  = __shfl(acc[r], src);   // per-lane src (bpermute)
                if (has && v > vm[r]) {   // uniform within each quad
                    const int qq = wave * 16 + quad * 4 + r;
                    if (l16 == 0) { pv[qq][pp[r]] = v; pix[qq][pp[r]] = n0 + (src & 15); }
                    // Recompute pool argmin: 16 lanes x 2 slots + 4-step butterfly.
                    float s0 = pv[qq][l16];
                    int   p0 = l16;
                    const float s1 = pv[qq][l16 + 16];
                    if (s1 < s0) { s0 = s1; p0 = l16 + 16; }
#pragma unroll
                    for (int off = 1; off < 16; off <<= 1) {
                        const float os = __shfl_xor(s0, off);
                        const int   op = __shfl_xor(p0, off);
                        if (os < s0) { s0 = os; p0 = op; }
                    }
                    vm[r] = s0; pp[r] = p0;
                }
                m &= ~clearm;
            }
        }
    }

    // Writeout (pools are wave-private; no barrier needed).
    for (int i = lane; i < 16 * TOPK_N; i += 64) {
        const int qq = i >> 5, ss = i & 31;
        cand[((size_t)(q0 + qq) * NSPLIT + blockIdx.y) * TOPK_N + ss] = pix[wave * 16 + qq][ss];
    }
}

// ---------------------------------------------------------------------------
// Kernel C: exact fp32 rescore of 256 candidates (sequential fmaf chain,
// bitwise-matches reference), bitonic sort (desc, tie -> lower idx), gather.
// One block (256 threads) per query.
// ---------------------------------------------------------------------------
__global__ __launch_bounds__(256) void rescore_gather_kernel(
    const float* __restrict__ qg, const float* __restrict__ keys,
    const float* __restrict__ values, const int* __restrict__ cand,
    float* __restrict__ out)
{
    __shared__ float qrow[DKDIM];
    __shared__ float ss[NCAND];
    __shared__ int   si[NCAND];
    const int bt  = blockIdx.x;
    const int tid = threadIdx.x;

    if (tid < DKDIM) qrow[tid] = qg[(size_t)bt * DKDIM + tid];
    __syncthreads();

    const int idx = cand[(size_t)bt * NCAND + tid];
    const float4* krow = (const float4*)(keys + (size_t)idx * DKDIM);
    float s = 0.f;
#pragma unroll
    for (int d4 = 0; d4 < DKDIM / 4; ++d4) {
        const float4 k4 = krow[d4];
        const float4 q4 = *(const float4*)&qrow[4 * d4];
        s = fmaf(q4.x, k4.x, s);
        s = fmaf(q4.y, k4.y, s);
        s = fmaf(q4.z, k4.z, s);
        s = fmaf(q4.w, k4.w, s);
    }
    ss[tid] = s; si[tid] = idx;
    __syncthreads();

    for (int k = 2; k <= NCAND; k <<= 1) {
        for (int j = k >> 1; j > 0; j >>= 1) {
            const int ixj = tid ^ j;
            if (ixj > tid) {
                const bool dirDesc = ((tid & k) == 0);
                const float sa = ss[tid], sb = ss[ixj];
                const int   ia = si[tid], ib = si[ixj];
                const bool before = (sa > sb) || (sa == sb && ia < ib);
                if (before != dirDesc) {
                    ss[tid] = sb; ss[ixj] = sa;
                    si[tid] = ib; si[ixj] = ia;
                }
            }
            __syncthreads();
        }
    }

    const int lane = tid & 31;
    const int rb   = tid >> 5;
#pragma unroll
    for (int r = 0; r < 4; ++r) {
        const int row = rb + 8 * r;
        const int n   = si[row];
        const float4 kv = *(const float4*)(keys   + (size_t)n * DKDIM + 4 * lane);
        const float4 vv = *(const float4*)(values + (size_t)n * DVDIM + 4 * lane);
        const size_t ob = ((size_t)bt * TOPK_N + row) * DKDIM + 4 * lane;
        *(float4*)(out + ob)        = kv;
        *(float4*)(out + NOUT + ob) = vv;
    }
}

extern "C" void kernel_launch(void* const* d_in, const int* in_sizes, int n_in,
                              void* d_out, int out_size, void* d_ws, size_t ws_size,
                              hipStream_t stream)
{
    const float* q      = (const float*)d_in[0];
    const float* keys   = (const float*)d_in[1];
    const float* values = (const float*)d_in[2];
    float* out = (float*)d_out;

    unsigned short* qbf = (unsigned short*)d_ws;                               // 1 MB
    unsigned short* kbf = (unsigned short*)((char*)d_ws + (1u << 20));         // 16 MB
    int* cand = (int*)((char*)d_ws + (17u << 20));                             // 4 MB

    const int cvt_groups = (NQ + NKEYS) * DKDIM / 8;
    convert_kernel<<<(cvt_groups + 255) / 256, 256, 0, stream>>>(q, keys, qbf, kbf);
    score_select_kernel<<<dim3(NQ / BQ, NSPLIT), 256, 0, stream>>>(qbf, kbf, cand);
    rescore_gather_kernel<<<NQ, 256, 0, stream>>>(q, keys, values, cand, out);
}